// Round 3
// baseline (450.612 us; speedup 1.0000x reference)
//
#include <hip/hip_runtime.h>

#define N_ACT 80
#define M_CON 85
#define PDHG_ITERS 200
#define POWER_ITERS 20
#define NRS 6    // row slots: i = (l&15) + 16*r  (r<6 -> i<96, valid i<85)
#define NCS 21   // col slots: j = (l>>4) + 4*c   (c<21; j==80 only on q==0,c==20)

// ---- cross-lane helpers ----
template<int CTRL>
__device__ __forceinline__ float dppf(float v) {
    return __int_as_float(
        __builtin_amdgcn_update_dpp(0, __float_as_int(v), CTRL, 0xF, 0xF, true));
}
// sum across the 16-lane DPP row (lanes sharing l>>4): row_ror 1,2,4,8
__device__ __forceinline__ float rowsum16(float v) {
    v += dppf<0x121>(v);
    v += dppf<0x122>(v);
    v += dppf<0x124>(v);
    v += dppf<0x128>(v);
    return v;
}
__device__ __forceinline__ float rowmin16(float v) {
    v = fminf(v, dppf<0x121>(v));
    v = fminf(v, dppf<0x122>(v));
    v = fminf(v, dppf<0x124>(v));
    v = fminf(v, dppf<0x128>(v));
    return v;
}
__device__ __forceinline__ float xs16(float v) {   // lane ^ 16 (within 32-group)
    return __int_as_float(__builtin_amdgcn_ds_swizzle(__float_as_int(v), 0x401F));
}
__device__ __forceinline__ float xb32(float v, int a32) {  // lane ^ 32
    return __int_as_float(__builtin_amdgcn_ds_bpermute(a32, __float_as_int(v)));
}
// sum across the 4 lanes sharing l&15 (masks 16, 32)
__device__ __forceinline__ float colsum4(float v, int a32) {
    v += xs16(v);
    v += xb32(v, a32);
    return v;
}

__global__ __launch_bounds__(64, 1) void cheby_proj_kernel(
    const float* __restrict__ x_hat, const float* __restrict__ A,
    const float* __restrict__ b, float* __restrict__ out)
{
    const int p  = blockIdx.x;
    const int l  = threadIdx.x;
    const int li = l & 15;          // i-chunk index
    const int q  = l >> 4;          // j residue mod 4
    const int a32 = (l ^ 32) << 2;  // bpermute byte address for lane^32

    // ---- load G fragment: g[r][c] = G[li+16r][q+4c]; slot c==20 holds d (q==0) ----
    float g[NRS][NCS];
    float bl[NRS];
    const float* Ap = A + (size_t)p * (M_CON * N_ACT);
#pragma unroll
    for (int r = 0; r < NRS; ++r) {
        const int i = li + 16 * r;
        const bool vi = (i < M_CON);
#pragma unroll
        for (int c = 0; c < 20; ++c) {
            const int j = q + 4 * c;                 // <= 79, always a valid column
            g[r][c] = vi ? Ap[i * N_ACT + j] : 0.f;
        }
        g[r][20] = 0.f;
        bl[r] = vi ? b[(size_t)p * M_CON + i] : 1e30f;
    }

    // ---- d_i = max(||A_i||, 1e-12) -> g[r][20] on q==0 lanes ----
#pragma unroll
    for (int r = 0; r < NRS; ++r) {
        float s = 0.f;
#pragma unroll
        for (int c = 0; c < 20; ++c) s += g[r][c] * g[r][c];
        s = colsum4(s, a32);
        if (q == 0 && li + 16 * r < M_CON) g[r][20] = fmaxf(sqrtf(s), 1e-12f);
    }

    // ---- power iteration: v <- GT(G v)/||GT(G v)||, v0 = ones(n+1) ----
    float v[NCS];
#pragma unroll
    for (int c = 0; c < NCS; ++c) v[c] = (q + 4 * c <= N_ACT) ? 1.f : 0.f;

#pragma unroll 1
    for (int it = 0; it < POWER_ITERS; ++it) {
        float gi[NRS];
#pragma unroll
        for (int r = 0; r < NRS; ++r) {
            float s0 = 0.f, s1 = 0.f;
#pragma unroll
            for (int c = 0; c < NCS; c += 2) s0 += g[r][c] * v[c];
#pragma unroll
            for (int c = 1; c < NCS; c += 2) s1 += g[r][c] * v[c];
            gi[r] = colsum4(s0 + s1, a32);           // replicated across q
        }
        float nrm = 0.f;
        float w[NCS];
#pragma unroll
        for (int c = 0; c < NCS; ++c) {
            float s = 0.f;
#pragma unroll
            for (int r = 0; r < NRS; ++r) s += g[r][c] * gi[r];
            s = rowsum16(s);                         // replicated within 16-row
            w[c] = s;
            nrm += s * s;
        }
        nrm = colsum4(nrm, a32);                     // total ||w||^2 everywhere
        const float inv = 1.f / (sqrtf(nrm) + 1e-12f);
#pragma unroll
        for (int c = 0; c < NCS; ++c) v[c] = w[c] * inv;
    }

    // ---- L = ||G v||; tau = sigma = 0.9/max(L,1e-6) ----
    float tau;
    {
        float L2 = 0.f;
#pragma unroll
        for (int r = 0; r < NRS; ++r) {
            float s0 = 0.f, s1 = 0.f;
#pragma unroll
            for (int c = 0; c < NCS; c += 2) s0 += g[r][c] * v[c];
#pragma unroll
            for (int c = 1; c < NCS; c += 2) s1 += g[r][c] * v[c];
            float s = colsum4(s0 + s1, a32);
            L2 += s * s;                             // i in {li+16r}: distinct per li
        }
        L2 = rowsum16(L2);                           // sum over all i
        tau = 0.9f / fmaxf(sqrtf(L2), 1e-6f);
    }

    // ---- PDHG ----
    float z[NCS], zb[NCS], y[NRS];
#pragma unroll
    for (int c = 0; c < NCS; ++c) z[c] = 0.f;
#pragma unroll
    for (int r = 0; r < NRS; ++r) y[r] = 0.f;

#pragma unroll 1
    for (int it = 0; it < PDHG_ITERS; ++it) {
        // z_new = relu(z - tau*(c + GT y)); zbar = 2 z_new - z
#pragma unroll
        for (int c = 0; c < NCS; ++c) {
            float s = 0.f;
#pragma unroll
            for (int r = 0; r < NRS; ++r) s += g[r][c] * y[r];
            s = rowsum16(s);                         // full col dot, replicated
            float t = fmaf(-tau, s, z[c]);
            if (c == 20) t += (q == 0) ? tau : 0.f;  // c_j = -1 at j == 80
            const float zn = fmaxf(t, 0.f);
            zb[c] = 2.f * zn - z[c];
            z[c] = zn;
        }
        // y = relu(y + tau*(G zbar - b))
#pragma unroll
        for (int r = 0; r < NRS; ++r) {
            float s0 = 0.f, s1 = 0.f;
#pragma unroll
            for (int c = 0; c < NCS; c += 2) s0 += g[r][c] * zb[c];
#pragma unroll
            for (int c = 1; c < NCS; c += 2) s1 += g[r][c] * zb[c];
            const float s = colsum4(s0 + s1, a32);
            y[r] = fmaxf(fmaf(tau, s - bl[r], y[r]), 0.f);
        }
    }

    // ---- alpha map (x0 = z[0..19] per residue; z[20] is the radius) ----
    float dv[20];
#pragma unroll
    for (int c = 0; c < 20; ++c)
        dv[c] = x_hat[(size_t)p * N_ACT + q + 4 * c] - z[c];

    const float FINF = __builtin_inff();
    float amin = FINF;
#pragma unroll
    for (int r = 0; r < NRS; ++r) {
        float ax = 0.f, ad = 0.f;
#pragma unroll
        for (int c = 0; c < 20; ++c) {
            ax += g[r][c] * z[c];
            ad += g[r][c] * dv[c];
        }
        ax = colsum4(ax, a32);
        ad = colsum4(ad, a32);
        if (li + 16 * r < M_CON) {
            const float slack = fmaxf(bl[r] - ax, 0.f);
            const float a = (ad > 0.f) ? slack / (ad + 1e-12f) : FINF;
            amin = fminf(amin, a);
        }
    }
    amin = rowmin16(amin);
    amin = fminf(amin, xs16(amin));
    amin = fminf(amin, xb32(amin, a32));

    float alpha = (amin < FINF) ? amin : 1.0f;       // !isfinite -> 1.0
    alpha = fminf(fmaxf(alpha - 1e-9f, 0.f), 1.0f);

    if (li == 0) {                                   // lanes 0,16,32,48 write residue q
#pragma unroll
        for (int c = 0; c < 20; ++c)
            out[(size_t)p * N_ACT + q + 4 * c] = fmaxf(fmaf(alpha, dv[c], z[c]), 0.f);
    }
}

extern "C" void kernel_launch(void* const* d_in, const int* in_sizes, int n_in,
                              void* d_out, int out_size, void* d_ws, size_t ws_size,
                              hipStream_t stream) {
    const float* x_hat = (const float*)d_in[0];
    const float* A     = (const float*)d_in[1];
    const float* b     = (const float*)d_in[2];
    float* out = (float*)d_out;
    const int P = in_sizes[0] / N_ACT;   // B*S = 1024
    cheby_proj_kernel<<<P, 64, 0, stream>>>(x_hat, A, b, out);
}

// Round 4
// 425.261 us; speedup vs baseline: 1.0596x; 1.0596x over previous
//
#include <hip/hip_runtime.h>

#define N_ACT 80
#define M_CON 85
#define PDHG_ITERS 200
#define POWER_ITERS 20
#define NRS 3    // row slots per lane: i = 48*w + li + 16*r
#define NCS 21   // col slots per lane: j = q + 4*c (c==20 -> j==80 only on q==0)

// ---- cross-lane helpers ----
template<int CTRL>
__device__ __forceinline__ float dppf(float v) {
    return __int_as_float(
        __builtin_amdgcn_update_dpp(0, __float_as_int(v), CTRL, 0xF, 0xF, true));
}
// sum/min across the 16 lanes sharing q (row_ror 1,2,4,8)
__device__ __forceinline__ float rowsum16(float v) {
    v += dppf<0x121>(v);
    v += dppf<0x122>(v);
    v += dppf<0x124>(v);
    v += dppf<0x128>(v);
    return v;
}
__device__ __forceinline__ float rowmin16(float v) {
    v = fminf(v, dppf<0x121>(v));
    v = fminf(v, dppf<0x122>(v));
    v = fminf(v, dppf<0x124>(v));
    v = fminf(v, dppf<0x128>(v));
    return v;
}
__device__ __forceinline__ float xs16(float v) {   // lane ^ 16
    return __int_as_float(__builtin_amdgcn_ds_swizzle(__float_as_int(v), 0x401F));
}
__device__ __forceinline__ float xb32(float v, int a32) {  // lane ^ 32
    return __int_as_float(__builtin_amdgcn_ds_bpermute(a32, __float_as_int(v)));
}
__device__ __forceinline__ float colsum4(float v, int a32) {  // across q
    v += xs16(v);
    v += xb32(v, a32);
    return v;
}

__global__ __launch_bounds__(128, 2) void cheby_proj_kernel(
    const float* __restrict__ x_hat, const float* __restrict__ A,
    const float* __restrict__ b, float* __restrict__ out)
{
    __shared__ __align__(16) float xch[2][4][24];  // [wave][q][c] partial exchange
    __shared__ float sch[2];                       // scalar exchange

    const int p  = blockIdx.x;
    const int t  = threadIdx.x;
    const int w  = t >> 6;          // wave id: 0 -> rows 0..47, 1 -> rows 48..84
    const int l  = t & 63;
    const int li = l & 15;          // row-chunk index within wave
    const int q  = l >> 4;          // column residue mod 4
    const int a32 = (l ^ 32) << 2;  // bpermute byte addr for lane^32
    const int ibase = 48 * w;

    // ---- load G fragment: g[r][c] = G[ibase+li+16r][q+4c]; c==20 holds d ----
    float g[NRS][NCS];
    float bl[NRS];
    const float* Ap = A + (size_t)p * (M_CON * N_ACT);
#pragma unroll
    for (int r = 0; r < NRS; ++r) {
        const int i = ibase + li + 16 * r;
        const bool vi = (i < M_CON);
#pragma unroll
        for (int c = 0; c < 20; ++c) {
            const int j = q + 4 * c;                 // <= 79, always valid
            g[r][c] = vi ? Ap[i * N_ACT + j] : 0.f;
        }
        g[r][20] = 0.f;
        bl[r] = vi ? b[(size_t)p * M_CON + i] : 1e30f;
    }

    // ---- d_i = max(||A_i||,1e-12) -> g[r][20] on q==0 (wave-local rows) ----
#pragma unroll
    for (int r = 0; r < NRS; ++r) {
        float s = 0.f;
#pragma unroll
        for (int c = 0; c < 20; ++c) s += g[r][c] * g[r][c];
        s = colsum4(s, a32);
        if (q == 0 && ibase + li + 16 * r < M_CON)
            g[r][20] = fmaxf(sqrtf(s), 1e-12f);
    }

    // ---- power iteration: v <- GT(G v)/||.||, v0 = ones(n+1) ----
    float v[NCS];
#pragma unroll
    for (int c = 0; c < NCS; ++c) v[c] = (q + 4 * c <= N_ACT) ? 1.f : 0.f;

#pragma unroll 1
    for (int it = 0; it < POWER_ITERS; ++it) {
        // gi = G v on this wave's rows (full row dots, wave-local)
        float gi[NRS];
#pragma unroll
        for (int r = 0; r < NRS; ++r) {
            float s = 0.f;
#pragma unroll
            for (int c = 0; c < NCS; ++c) s += g[r][c] * v[c];
            gi[r] = colsum4(s, a32);
        }
        // wave-partial of w_j = sum_i g[i][j] gi_i
        float pw[NCS];
#pragma unroll
        for (int c = 0; c < NCS; ++c) {
            float s = 0.f;
#pragma unroll
            for (int r = 0; r < NRS; ++r) s += g[r][c] * gi[r];
            pw[c] = rowsum16(s);
        }
        if (li == 0) {
            float4* dst = (float4*)&xch[w][q][0];
            dst[0] = make_float4(pw[0],  pw[1],  pw[2],  pw[3]);
            dst[1] = make_float4(pw[4],  pw[5],  pw[6],  pw[7]);
            dst[2] = make_float4(pw[8],  pw[9],  pw[10], pw[11]);
            dst[3] = make_float4(pw[12], pw[13], pw[14], pw[15]);
            dst[4] = make_float4(pw[16], pw[17], pw[18], pw[19]);
            xch[w][q][20] = pw[20];
        }
        __syncthreads();
        {
            const float4* src = (const float4*)&xch[1 ^ w][q][0];
            float4 o0 = src[0], o1 = src[1], o2 = src[2], o3 = src[3], o4 = src[4];
            float  o20 = xch[1 ^ w][q][20];
            pw[0] += o0.x;  pw[1] += o0.y;  pw[2] += o0.z;  pw[3] += o0.w;
            pw[4] += o1.x;  pw[5] += o1.y;  pw[6] += o1.z;  pw[7] += o1.w;
            pw[8] += o2.x;  pw[9] += o2.y;  pw[10] += o2.z; pw[11] += o2.w;
            pw[12] += o3.x; pw[13] += o3.y; pw[14] += o3.z; pw[15] += o3.w;
            pw[16] += o4.x; pw[17] += o4.y; pw[18] += o4.z; pw[19] += o4.w;
            pw[20] += o20;
        }
        __syncthreads();
        float nrm = 0.f;
#pragma unroll
        for (int c = 0; c < NCS; ++c) nrm += pw[c] * pw[c];
        nrm = colsum4(nrm, a32);                     // sum over all j
        const float inv = 1.f / (sqrtf(nrm) + 1e-12f);
#pragma unroll
        for (int c = 0; c < NCS; ++c) v[c] = pw[c] * inv;
    }

    // ---- L = ||G v||; tau = sigma = 0.9/max(L,1e-6) ----
    float tau;
    {
        float L2p = 0.f;
#pragma unroll
        for (int r = 0; r < NRS; ++r) {
            float s = 0.f;
#pragma unroll
            for (int c = 0; c < NCS; ++c) s += g[r][c] * v[c];
            s = colsum4(s, a32);
            L2p += s * s;
        }
        L2p = rowsum16(L2p);                         // sum over this wave's rows
        if (l == 0) sch[w] = L2p;
        __syncthreads();
        const float L2 = sch[0] + sch[1];
        tau = 0.9f / fmaxf(sqrtf(L2), 1e-6f);
        __syncthreads();
    }

    // ---- PDHG: z replicated in both waves; y wave-local ----
    float z[NCS], zb[NCS], y[NRS];
#pragma unroll
    for (int c = 0; c < NCS; ++c) z[c] = 0.f;
#pragma unroll
    for (int r = 0; r < NRS; ++r) y[r] = 0.f;

#pragma unroll 1
    for (int it = 0; it < PDHG_ITERS; ++it) {
        // wave-partial column dots: (GT y)_j over this wave's rows
        float pz[NCS];
#pragma unroll
        for (int c = 0; c < NCS; ++c) {
            float s = 0.f;
#pragma unroll
            for (int r = 0; r < NRS; ++r) s += g[r][c] * y[r];
            pz[c] = rowsum16(s);
        }
        if (li == 0) {
            float4* dst = (float4*)&xch[w][q][0];
            dst[0] = make_float4(pz[0],  pz[1],  pz[2],  pz[3]);
            dst[1] = make_float4(pz[4],  pz[5],  pz[6],  pz[7]);
            dst[2] = make_float4(pz[8],  pz[9],  pz[10], pz[11]);
            dst[3] = make_float4(pz[12], pz[13], pz[14], pz[15]);
            dst[4] = make_float4(pz[16], pz[17], pz[18], pz[19]);
            xch[w][q][20] = pz[20];
        }
        __syncthreads();
        {
            const float4* src = (const float4*)&xch[1 ^ w][q][0];
            float4 o0 = src[0], o1 = src[1], o2 = src[2], o3 = src[3], o4 = src[4];
            float  o20 = xch[1 ^ w][q][20];
            pz[0] += o0.x;  pz[1] += o0.y;  pz[2] += o0.z;  pz[3] += o0.w;
            pz[4] += o1.x;  pz[5] += o1.y;  pz[6] += o1.z;  pz[7] += o1.w;
            pz[8] += o2.x;  pz[9] += o2.y;  pz[10] += o2.z; pz[11] += o2.w;
            pz[12] += o3.x; pz[13] += o3.y; pz[14] += o3.z; pz[15] += o3.w;
            pz[16] += o4.x; pz[17] += o4.y; pz[18] += o4.z; pz[19] += o4.w;
            pz[20] += o20;
        }
        __syncthreads();
        // z-update (identical in both waves)
#pragma unroll
        for (int c = 0; c < NCS; ++c) {
            float tv = fmaf(-tau, pz[c], z[c]);
            if (c == 20) tv += (q == 0) ? tau : 0.f;   // c_j = -1 at j==80
            const float zn = fmaxf(tv, 0.f);
            zb[c] = 2.f * zn - z[c];
            z[c] = zn;
        }
        // y-update (wave-local full row dots)
#pragma unroll
        for (int r = 0; r < NRS; ++r) {
            float s = 0.f;
#pragma unroll
            for (int c = 0; c < NCS; ++c) s += g[r][c] * zb[c];
            s = colsum4(s, a32);
            y[r] = fmaxf(fmaf(tau, s - bl[r], y[r]), 0.f);
        }
    }

    // ---- alpha map (x0 = z[0..19]; z[20] is the radius) ----
    float dv[20];
#pragma unroll
    for (int c = 0; c < 20; ++c)
        dv[c] = x_hat[(size_t)p * N_ACT + q + 4 * c] - z[c];

    const float FINF = __builtin_inff();
    float amin = FINF;
#pragma unroll
    for (int r = 0; r < NRS; ++r) {
        float ax = 0.f, ad = 0.f;
#pragma unroll
        for (int c = 0; c < 20; ++c) {
            ax += g[r][c] * z[c];
            ad += g[r][c] * dv[c];
        }
        ax = colsum4(ax, a32);
        ad = colsum4(ad, a32);
        if (ibase + li + 16 * r < M_CON) {
            const float slack = fmaxf(bl[r] - ax, 0.f);
            const float a = (ad > 0.f) ? slack / (ad + 1e-12f) : FINF;
            amin = fminf(amin, a);
        }
    }
    amin = rowmin16(amin);
    amin = fminf(amin, xs16(amin));
    amin = fminf(amin, xb32(amin, a32));
    if (l == 0) sch[w] = amin;
    __syncthreads();
    float am = fminf(sch[0], sch[1]);

    float alpha = (am < FINF) ? am : 1.0f;           // !isfinite -> 1.0
    alpha = fminf(fmaxf(alpha - 1e-9f, 0.f), 1.0f);

    if (w == 0 && li == 0) {                         // lanes q=0..3 write residue q
#pragma unroll
        for (int c = 0; c < 20; ++c)
            out[(size_t)p * N_ACT + q + 4 * c] = fmaxf(fmaf(alpha, dv[c], z[c]), 0.f);
    }
}

extern "C" void kernel_launch(void* const* d_in, const int* in_sizes, int n_in,
                              void* d_out, int out_size, void* d_ws, size_t ws_size,
                              hipStream_t stream) {
    const float* x_hat = (const float*)d_in[0];
    const float* A     = (const float*)d_in[1];
    const float* b     = (const float*)d_in[2];
    float* out = (float*)d_out;
    const int P = in_sizes[0] / N_ACT;   // B*S = 1024
    cheby_proj_kernel<<<P, 128, 0, stream>>>(x_hat, A, b, out);
}

// Round 5
// 307.861 us; speedup vs baseline: 1.4637x; 1.3813x over previous
//
#include <hip/hip_runtime.h>

#define N_ACT 80
#define M_CON 85
#define PDHG_ITERS 200
#define POWER_ITERS 20
#define NRT 6    // row slots per lane: i = 48*w + ti + 8*r
#define NCT 11   // col slots per lane: j = tj + 8*c (c==10 -> j==80 only on tj==0)

// lane layout: l = ti*8 + tj; tj = l&7 (cols), ti = l>>3 (rows)

template<int CTRL>
__device__ __forceinline__ float dpp_add(float v) {
    return v + __int_as_float(__builtin_amdgcn_update_dpp(
        0, __float_as_int(v), CTRL, 0xF, 0xF, true));
}
template<int CTRL>
__device__ __forceinline__ float dpp_min(float v) {
    return fminf(v, __int_as_float(__builtin_amdgcn_update_dpp(
        0, __float_as_int(v), CTRL, 0xF, 0xF, true)));
}
// sum/min over tj (lane bits 0..2): quad_perm xor1 (0xB1), xor2 (0x4E),
// then row_half_mirror (0x141) pairs the two quad-sums within each 8-group.
__device__ __forceinline__ float tjsum(float v) {
    v = dpp_add<0xB1>(v);
    v = dpp_add<0x4E>(v);
    v = dpp_add<0x141>(v);
    return v;
}
__device__ __forceinline__ float tjmin(float v) {
    v = dpp_min<0xB1>(v);
    v = dpp_min<0x4E>(v);
    v = dpp_min<0x141>(v);
    return v;
}
template<int PAT>
__device__ __forceinline__ float swz(float v) {
    return __int_as_float(__builtin_amdgcn_ds_swizzle(__float_as_int(v), PAT));
}
__device__ __forceinline__ float bperm32(float v, int a32) {
    return __int_as_float(__builtin_amdgcn_ds_bpermute(a32, __float_as_int(v)));
}
// sum/min over ti (lane bits 3..5): xor8 (0x201F), xor16 (0x401F), xor32 (bpermute)
__device__ __forceinline__ float tisum(float v, int a32) {
    v += swz<0x201F>(v);
    v += swz<0x401F>(v);
    v += bperm32(v, a32);
    return v;
}
__device__ __forceinline__ float timin(float v, int a32) {
    v = fminf(v, swz<0x201F>(v));
    v = fminf(v, swz<0x401F>(v));
    v = fminf(v, bperm32(v, a32));
    return v;
}

__device__ __forceinline__ void pack11(float* dst, const float* s) {
    ((float4*)dst)[0] = make_float4(s[0], s[1], s[2], s[3]);
    ((float4*)dst)[1] = make_float4(s[4], s[5], s[6], s[7]);
    ((float2*)dst)[4] = make_float2(s[8], s[9]);
    dst[10] = s[10];
}
__device__ __forceinline__ void unpack11(float* d, const float* src) {
    float4 a4 = ((const float4*)src)[0];
    float4 b4 = ((const float4*)src)[1];
    float2 c2 = ((const float2*)src)[4];
    d[0] = a4.x; d[1] = a4.y; d[2] = a4.z; d[3] = a4.w;
    d[4] = b4.x; d[5] = b4.y; d[6] = b4.z; d[7] = b4.w;
    d[8] = c2.x; d[9] = c2.y; d[10] = src[10];
}

__global__ __launch_bounds__(128, 2) void cheby_proj_kernel(
    const float* __restrict__ x_hat, const float* __restrict__ A,
    const float* __restrict__ b, float* __restrict__ out)
{
    __shared__ __align__(16) float xch[2][2][8][12];  // [parity][wave][tj][slot]
    __shared__ float sch[2];

    const int p  = blockIdx.x;
    const int t  = threadIdx.x;
    const int w  = t >> 6;           // wave 0: rows 0..47, wave 1: rows 48..84
    const int l  = t & 63;
    const int tj = l & 7;            // column group
    const int ti = l >> 3;           // row group within wave
    const int a32 = (l ^ 32) << 2;   // bpermute byte addr for lane^32
    const int ibase = 48 * w;

    // ---- load G fragment: g[r][c] = G[ibase+ti+8r][tj+8c]; (tj==0,c==10) = d ----
    float g[NRT][NCT];
    float bl[NRT];
    const float* Ap = A + (size_t)p * (M_CON * N_ACT);
#pragma unroll
    for (int r = 0; r < NRT; ++r) {
        const int i = ibase + ti + 8 * r;
        const bool vi = (i < M_CON);
#pragma unroll
        for (int c = 0; c < 10; ++c) {
            const int j = tj + 8 * c;                // <= 79, always valid
            g[r][c] = vi ? Ap[i * N_ACT + j] : 0.f;
        }
        g[r][10] = 0.f;
        bl[r] = vi ? b[(size_t)p * M_CON + i] : 1e30f;
    }

    // ---- d_i = max(||A_i||,1e-12) -> g[r][10] on tj==0 lanes ----
#pragma unroll
    for (int r = 0; r < NRT; ++r) {
        float s = 0.f;
#pragma unroll
        for (int c = 0; c < 10; ++c) s += g[r][c] * g[r][c];
        s = tjsum(s);
        if (tj == 0 && ibase + ti + 8 * r < M_CON)
            g[r][10] = fmaxf(sqrtf(s), 1e-12f);
    }

    // ---- power iteration: v <- GT(G v)/||.||, v0 = ones on valid j ----
    float v[NCT];
#pragma unroll
    for (int c = 0; c < NCT; ++c) v[c] = (tj + 8 * c <= N_ACT) ? 1.f : 0.f;

    auto pow_iter = [&](int par) {
        float gi[NRT];
#pragma unroll
        for (int r = 0; r < NRT; ++r) {
            float s = 0.f;
#pragma unroll
            for (int c = 0; c < NCT; ++c) s = fmaf(g[r][c], v[c], s);
            gi[r] = tjsum(s);                        // replicated across tj
        }
        float pw[NCT];
#pragma unroll
        for (int c = 0; c < NCT; ++c) {
            float s = 0.f;
#pragma unroll
            for (int r = 0; r < NRT; ++r) s = fmaf(g[r][c], gi[r], s);
            pw[c] = tisum(s, a32);                   // wave-partial, ti-replicated
        }
        if (ti == 0) pack11(&xch[par][w][tj][0], pw);
        __syncthreads();
        float po[NCT];
        unpack11(po, &xch[par][1 ^ w][tj][0]);
        float nrm = 0.f;
#pragma unroll
        for (int c = 0; c < NCT; ++c) {
            pw[c] += po[c];
            nrm = fmaf(pw[c], pw[c], nrm);
        }
        nrm = tjsum(nrm);                            // total ||w||^2 (all lanes)
        const float inv = 1.f / (sqrtf(nrm) + 1e-12f);
#pragma unroll
        for (int c = 0; c < NCT; ++c) v[c] = pw[c] * inv;
    };
#pragma unroll 1
    for (int it2 = 0; it2 < POWER_ITERS / 2; ++it2) { pow_iter(0); pow_iter(1); }

    // ---- L = ||G v||; tau = sigma = 0.9/max(L,1e-6) ----
    float tau;
    {
        float L2p = 0.f;
#pragma unroll
        for (int r = 0; r < NRT; ++r) {
            float s = 0.f;
#pragma unroll
            for (int c = 0; c < NCT; ++c) s = fmaf(g[r][c], v[c], s);
            s = tjsum(s);
            L2p = fmaf(s, s, L2p);                   // distinct per ti
        }
        L2p = tisum(L2p, a32);                       // this wave's rows
        if (l == 0) sch[w] = L2p;
        __syncthreads();
        tau = 0.9f / fmaxf(sqrtf(sch[0] + sch[1]), 1e-6f);
        __syncthreads();
    }

    // ---- PDHG: z/zb replicated in both waves; y wave-local ----
    float z[NCT], zb[NCT], y[NRT];
#pragma unroll
    for (int c = 0; c < NCT; ++c) z[c] = 0.f;
#pragma unroll
    for (int r = 0; r < NRT; ++r) y[r] = 0.f;
    const float ctau = (tj == 0) ? tau : 0.f;        // c_j = -1 at j==80
    const float ntau = -tau;

    auto pdhg_iter = [&](int par) {
        // wave-partial (GT y)_j, reduced over this wave's ti groups
        float pz[NCT];
#pragma unroll
        for (int c = 0; c < NCT; ++c) {
            float s = 0.f;
#pragma unroll
            for (int r = 0; r < NRT; ++r) s = fmaf(g[r][c], y[r], s);
            pz[c] = tisum(s, a32);
        }
        if (ti == 0) pack11(&xch[par][w][tj][0], pz);
        __syncthreads();
        float po[NCT];
        unpack11(po, &xch[par][1 ^ w][tj][0]);
        // z-update (identical in both waves)
#pragma unroll
        for (int c = 0; c < NCT; ++c) {
            float tt = fmaf(ntau, po[c], fmaf(ntau, pz[c], z[c]));
            if (c == 10) tt += ctau;
            const float zn = fmaxf(tt, 0.f);
            zb[c] = fmaf(2.f, zn, -z[c]);
            z[c] = zn;
        }
        // y-update (wave-local rows, full column span)
#pragma unroll
        for (int r = 0; r < NRT; ++r) {
            float s = 0.f;
#pragma unroll
            for (int c = 0; c < NCT; ++c) s = fmaf(g[r][c], zb[c], s);
            s = tjsum(s);
            y[r] = fmaxf(fmaf(tau, s - bl[r], y[r]), 0.f);
        }
    };
#pragma unroll 1
    for (int it2 = 0; it2 < PDHG_ITERS / 2; ++it2) { pdhg_iter(0); pdhg_iter(1); }

    // ---- alpha map (x components are slots c<10; z[10] is the radius) ----
    float dv[10];
#pragma unroll
    for (int c = 0; c < 10; ++c)
        dv[c] = x_hat[(size_t)p * N_ACT + tj + 8 * c] - z[c];

    const float FINF = __builtin_inff();
    float amin = FINF;
#pragma unroll
    for (int r = 0; r < NRT; ++r) {
        float ax = 0.f, ad = 0.f;
#pragma unroll
        for (int c = 0; c < 10; ++c) {               // exclude d column
            ax = fmaf(g[r][c], z[c], ax);
            ad = fmaf(g[r][c], dv[c], ad);
        }
        ax = tjsum(ax);
        ad = tjsum(ad);
        // invalid rows (i>=85): g==0 -> ad==0 -> INF automatically
        const float slack = fmaxf(bl[r] - ax, 0.f);
        const float a = (ad > 0.f) ? slack / (ad + 1e-12f) : FINF;
        amin = fminf(amin, a);
    }
    amin = timin(amin, a32);
    if (l == 0) sch[w] = amin;
    __syncthreads();
    const float am = fminf(sch[0], sch[1]);

    float alpha = (am < FINF) ? am : 1.0f;           // !isfinite -> 1.0
    alpha = fminf(fmaxf(alpha - 1e-9f, 0.f), 1.0f);

    if (w == 0 && ti == 0) {                         // 8 lanes write their tj residues
#pragma unroll
        for (int c = 0; c < 10; ++c)
            out[(size_t)p * N_ACT + tj + 8 * c] = fmaxf(fmaf(alpha, dv[c], z[c]), 0.f);
    }
}

extern "C" void kernel_launch(void* const* d_in, const int* in_sizes, int n_in,
                              void* d_out, int out_size, void* d_ws, size_t ws_size,
                              hipStream_t stream) {
    const float* x_hat = (const float*)d_in[0];
    const float* A     = (const float*)d_in[1];
    const float* b     = (const float*)d_in[2];
    float* out = (float*)d_out;
    const int P = in_sizes[0] / N_ACT;   // B*S = 1024
    cheby_proj_kernel<<<P, 128, 0, stream>>>(x_hat, A, b, out);
}

// Round 6
// 293.611 us; speedup vs baseline: 1.5347x; 1.0485x over previous
//
#include <hip/hip_runtime.h>

#define N_ACT 80
#define M_CON 85
#define PDHG_ITERS 200
#define POWER_ITERS 20
#define NRT 11   // row slots per lane: i = ri + 8*r   (r==10 invalid for ri>=5)
#define NCT 11   // col slots per lane: j = cj + 8*c   (c==10 -> j==80 only on cj==0)

// lane layout: l = cj*8 + ri; ri = l&7 (row group), cj = l>>3 (col group)
// reduce over ri (bits 0..2): pure DPP  (quad_perm xor1, xor2, row_half_mirror)
// reduce over cj (bits 3..5): DPP ror8 (xor8) + ds_swizzle xor16 + bpermute xor32

template<int CTRL>
__device__ __forceinline__ float dpp_add(float v) {
    return v + __int_as_float(__builtin_amdgcn_update_dpp(
        0, __float_as_int(v), CTRL, 0xF, 0xF, true));
}
template<int CTRL>
__device__ __forceinline__ float dpp_min(float v) {
    return fminf(v, __int_as_float(__builtin_amdgcn_update_dpp(
        0, __float_as_int(v), CTRL, 0xF, 0xF, true)));
}
template<int PAT>
__device__ __forceinline__ float swz(float v) {
    return __int_as_float(__builtin_amdgcn_ds_swizzle(__float_as_int(v), PAT));
}
__device__ __forceinline__ float bperm32(float v, int a32) {
    return __int_as_float(__builtin_amdgcn_ds_bpermute(a32, __float_as_int(v)));
}
// sum/min over ri: xor1 (0xB1), xor2 (0x4E), xor4 (row_half_mirror 0x141)
__device__ __forceinline__ float risum(float v) {
    v = dpp_add<0xB1>(v);
    v = dpp_add<0x4E>(v);
    v = dpp_add<0x141>(v);
    return v;
}
__device__ __forceinline__ float rimin(float v) {
    v = dpp_min<0xB1>(v);
    v = dpp_min<0x4E>(v);
    v = dpp_min<0x141>(v);
    return v;
}
// sum/min over cj: xor8 (row_ror:8 0x128), xor16 (swizzle), xor32 (bpermute)
__device__ __forceinline__ float cjsum(float v, int a32) {
    v = dpp_add<0x128>(v);
    v += swz<0x401F>(v);
    v += bperm32(v, a32);
    return v;
}
__device__ __forceinline__ float cjmin(float v, int a32) {
    v = dpp_min<0x128>(v);
    v = fminf(v, swz<0x401F>(v));
    v = fminf(v, bperm32(v, a32));
    return v;
}

__global__ __launch_bounds__(64, 1) void cheby_proj_kernel(
    const float* __restrict__ x_hat, const float* __restrict__ A,
    const float* __restrict__ b, float* __restrict__ out)
{
    const int p  = blockIdx.x;
    const int l  = threadIdx.x;
    const int ri = l & 7;            // row group (low bits -> DPP reduce)
    const int cj = l >> 3;           // col group (high bits -> DS reduce)
    const int a32 = (l ^ 32) << 2;   // bpermute byte addr for lane^32

    // ---- load G fragment: g[r][c] = G[ri+8r][cj+8c]; (cj==0,c==10) = d ----
    float g[NRT][NCT];
    float bl[NRT];
    const float* Ap = A + (size_t)p * (M_CON * N_ACT);
#pragma unroll
    for (int r = 0; r < NRT; ++r) {
        const int i = ri + 8 * r;
        const bool vi = (i < M_CON);
#pragma unroll
        for (int c = 0; c < 10; ++c) {
            const int j = cj + 8 * c;                // <= 79, always valid
            g[r][c] = vi ? Ap[i * N_ACT + j] : 0.f;
        }
        g[r][10] = 0.f;
        bl[r] = vi ? b[(size_t)p * M_CON + i] : 1e30f;
    }

    // ---- d_i = max(||A_i||,1e-12) -> g[r][10] on cj==0 lanes ----
#pragma unroll
    for (int r = 0; r < NRT; ++r) {
        float s = 0.f;
#pragma unroll
        for (int c = 0; c < 10; ++c) s = fmaf(g[r][c], g[r][c], s);
        s = cjsum(s, a32);
        if (cj == 0 && ri + 8 * r < M_CON)
            g[r][10] = fmaxf(sqrtf(s), 1e-12f);
    }

    // ---- power iteration: v <- GT(G v)/||.||, v0 = ones on valid j ----
    float v[NCT];
#pragma unroll
    for (int c = 0; c < NCT; ++c) v[c] = (cj + 8 * c <= N_ACT) ? 1.f : 0.f;

#pragma unroll 1
    for (int it = 0; it < POWER_ITERS; ++it) {
        float gi[NRT];
#pragma unroll
        for (int r = 0; r < NRT; ++r) {
            float s = 0.f;
#pragma unroll
            for (int c = 0; c < NCT; ++c) s = fmaf(g[r][c], v[c], s);
            gi[r] = cjsum(s, a32);                   // replicated across cj
        }
        float pw[NCT];
        float nrm = 0.f;
#pragma unroll
        for (int c = 0; c < NCT; ++c) {
            float s = 0.f;
#pragma unroll
            for (int r = 0; r < NRT; ++r) s = fmaf(g[r][c], gi[r], s);
            s = risum(s);                            // full col dot, ri-replicated
            pw[c] = s;
            nrm = fmaf(s, s, nrm);
        }
        nrm = cjsum(nrm, a32);                       // total ||w||^2 everywhere
        const float inv = 1.f / (sqrtf(nrm) + 1e-12f);
#pragma unroll
        for (int c = 0; c < NCT; ++c) v[c] = pw[c] * inv;
    }

    // ---- L = ||G v||; tau = sigma = 0.9/max(L,1e-6) ----
    float tau;
    {
        float L2 = 0.f;
#pragma unroll
        for (int r = 0; r < NRT; ++r) {
            float s = 0.f;
#pragma unroll
            for (int c = 0; c < NCT; ++c) s = fmaf(g[r][c], v[c], s);
            s = cjsum(s, a32);                       // row dot, distinct per ri,r
            L2 = fmaf(s, s, L2);
        }
        L2 = risum(L2);                              // sum over all rows
        tau = 0.9f / fmaxf(sqrtf(L2), 1e-6f);
    }

    // ---- PDHG ----
    float z[NCT], zb[NCT], y[NRT];
#pragma unroll
    for (int c = 0; c < NCT; ++c) z[c] = 0.f;
#pragma unroll
    for (int r = 0; r < NRT; ++r) y[r] = 0.f;
    const float ctau = (cj == 0) ? tau : 0.f;        // c_j = -1 at j==80
    const float ntau = -tau;

#pragma unroll 1
    for (int it = 0; it < PDHG_ITERS; ++it) {
        // z_new = relu(z - tau*(c + GT y)); zbar = 2 z_new - z  (pure-DPP reduce)
#pragma unroll
        for (int c = 0; c < NCT; ++c) {
            float s = 0.f;
#pragma unroll
            for (int r = 0; r < NRT; ++r) s = fmaf(g[r][c], y[r], s);
            s = risum(s);                            // full col dot (all 88 rows)
            float tt = fmaf(ntau, s, z[c]);
            if (c == 10) tt += ctau;
            const float zn = fmaxf(tt, 0.f);
            zb[c] = fmaf(2.f, zn, -z[c]);
            z[c] = zn;
        }
        // y = relu(y + tau*(G zbar - b))  (DS reduce over cj)
#pragma unroll
        for (int r = 0; r < NRT; ++r) {
            float s = 0.f;
#pragma unroll
            for (int c = 0; c < NCT; ++c) s = fmaf(g[r][c], zb[c], s);
            s = cjsum(s, a32);                       // row dot, cj-replicated
            y[r] = fmaxf(fmaf(tau, s - bl[r], y[r]), 0.f);
        }
    }

    // ---- alpha map (x components are slots c<10; z[10] is the radius) ----
    float dv[10];
#pragma unroll
    for (int c = 0; c < 10; ++c)
        dv[c] = x_hat[(size_t)p * N_ACT + cj + 8 * c] - z[c];

    const float FINF = __builtin_inff();
    float amin = FINF;
#pragma unroll
    for (int r = 0; r < NRT; ++r) {
        float ax = 0.f, ad = 0.f;
#pragma unroll
        for (int c = 0; c < 10; ++c) {               // exclude d column
            ax = fmaf(g[r][c], z[c], ax);
            ad = fmaf(g[r][c], dv[c], ad);
        }
        ax = cjsum(ax, a32);
        ad = cjsum(ad, a32);
        // invalid rows (i>=85): g==0 -> ad==0 -> INF automatically
        const float slack = fmaxf(bl[r] - ax, 0.f);
        const float a = (ad > 0.f) ? slack / (ad + 1e-12f) : FINF;
        amin = fminf(amin, a);
    }
    amin = rimin(amin);                              // global min, all lanes

    float alpha = (amin < FINF) ? amin : 1.0f;       // !isfinite -> 1.0
    alpha = fminf(fmaxf(alpha - 1e-9f, 0.f), 1.0f);

    if (ri == 0) {                                   // 8 lanes write their cj residues
#pragma unroll
        for (int c = 0; c < 10; ++c)
            out[(size_t)p * N_ACT + cj + 8 * c] = fmaxf(fmaf(alpha, dv[c], z[c]), 0.f);
    }
}

extern "C" void kernel_launch(void* const* d_in, const int* in_sizes, int n_in,
                              void* d_out, int out_size, void* d_ws, size_t ws_size,
                              hipStream_t stream) {
    const float* x_hat = (const float*)d_in[0];
    const float* A     = (const float*)d_in[1];
    const float* b     = (const float*)d_in[2];
    float* out = (float*)d_out;
    const int P = in_sizes[0] / N_ACT;   // B*S = 1024
    cheby_proj_kernel<<<P, 64, 0, stream>>>(x_hat, A, b, out);
}